// Round 5
// baseline (568.354 us; speedup 1.0000x reference)
//
#include <hip/hip_runtime.h>
#include <hip/hip_bf16.h>
#include <stdint.h>

#define DEV __device__ __forceinline__

// ---- constants for this problem ----
#define Bn 4
#define Sn 2048
#define Dn 1024
#define Hn 16
#define DHn 64
#define Mn (Bn*Sn)   // 8192

typedef __attribute__((ext_vector_type(8))) __bf16   bf16x8;
typedef __attribute__((ext_vector_type(4))) __bf16   bf16x4;
typedef __attribute__((ext_vector_type(4))) float    f32x4;
typedef __attribute__((ext_vector_type(8))) uint16_t u16x8;
typedef __attribute__((ext_vector_type(4))) uint16_t u16x4;
typedef __attribute__((ext_vector_type(4))) short    s16x4;

DEV uint16_t f2bf_bits(float f) {
    union { float f; uint32_t u; } v; v.f = f;
    uint32_t r = v.u + 0x7FFFu + ((v.u >> 16) & 1u);
    return (uint16_t)(r >> 16);
}
DEV float bf2f(uint16_t b) {
    union { uint32_t u; float f; } v; v.u = ((uint32_t)b) << 16;
    return v.f;
}

// pair float->bf16 via hardware v_cvt_pk_bf16_f32
DEV uint32_t cvt2bf(float a, float b) {
    __hip_bfloat162 h2 = __float22bfloat162_rn(float2{a, b});
    uint32_t u; __builtin_memcpy(&u, &h2, 4); return u;
}

DEV void load16_to_lds(const void* gsrc, void* ldst) {
    __builtin_amdgcn_global_load_lds(
        (const __attribute__((address_space(1))) uint32_t*)gsrc,
        (__attribute__((address_space(3))) uint32_t*)ldst,
        16, 0, 0);
}

DEV f32x4 mfma16(bf16x8 a, bf16x8 b, f32x4 c) {
    return __builtin_amdgcn_mfma_f32_16x16x32_bf16(a, b, c, 0, 0, 0);
}

// 16x16x16 bf16 MFMA (A,B = 4 bf16 per lane)
DEV f32x4 mfma16k16(u16x4 a_bits, u16x4 b_bits, f32x4 c) {
#if __has_builtin(__builtin_amdgcn_mfma_f32_16x16x16_bf16)
    bf16x4 a, b;
    __builtin_memcpy(&a, &a_bits, 8);
    __builtin_memcpy(&b, &b_bits, 8);
    return __builtin_amdgcn_mfma_f32_16x16x16_bf16(a, b, c, 0, 0, 0);
#else
    s16x4 a, b;
    __builtin_memcpy(&a, &a_bits, 8);
    __builtin_memcpy(&b, &b_bits, 8);
    return __builtin_amdgcn_mfma_f32_16x16x16bf16_1k(a, b, c, 0, 0, 0);
#endif
}

// ---------------- elementwise: cast x fp32 -> bf16 ----------------
__global__ void cast_x_k(const float* __restrict__ x, uint16_t* __restrict__ xb) {
    size_t i = ((size_t)blockIdx.x * 256 + threadIdx.x) * 4;
    f32x4 v = *(const f32x4*)(x + i);
    u16x4 o;
    #pragma unroll
    for (int j = 0; j < 4; j++) o[j] = f2bf_bits(v[j]);
    *(u16x4*)(xb + i) = o;
}

// ---------------- transpose+cast weights: Wt[n][k] = bf16(W[k][n]) ----------------
__global__ void transpose_cast_w(const float* __restrict__ W0, const float* __restrict__ W1,
                                 const float* __restrict__ W2, const float* __restrict__ W3,
                                 uint16_t* __restrict__ WtAll) {
    __shared__ float tile[32][33];
    const float* Ws[4] = {W0, W1, W2, W3};
    const float* W = Ws[blockIdx.z];
    uint16_t* Wt = WtAll + (size_t)blockIdx.z * Dn * Dn;
    int tx = threadIdx.x, ty = threadIdx.y;
    int n0 = blockIdx.x * 32, k0 = blockIdx.y * 32;
    tile[ty][tx] = W[(size_t)(k0 + ty) * Dn + n0 + tx];
    __syncthreads();
    Wt[(size_t)(n0 + ty) * Dn + k0 + tx] = f2bf_bits(tile[tx][ty]);
}

// ---------------- rope table ----------------
__global__ void rope_table_k(float* __restrict__ ct, float* __restrict__ st) {
    int i = blockIdx.x * 256 + threadIdx.x;   // 0..65535
    int s = i >> 5, f = i & 31;
    float inv = powf(10000.0f, -(float)f / 32.0f);
    float a = (float)s * inv;
    ct[i] = cosf(a);
    st[i] = sinf(a);
}

// ---------------- rope apply (in-place on Q or K); Q also scaled by 1/8 ----------------
__global__ void rope_apply_k(uint16_t* __restrict__ Q, uint16_t* __restrict__ Kt,
                             const float* __restrict__ ct, const float* __restrict__ st) {
    int idx = blockIdx.x * 256 + threadIdx.x;   // 0..1048575 (8192 rows * 128 chunks)
    uint16_t* ptr = (blockIdx.y == 0) ? Q : Kt;
    const float scale = (blockIdx.y == 0) ? 0.125f : 1.0f;
    int row = idx >> 7, c = idx & 127;
    int s = row & (Sn - 1);
    int i0 = (c & 7) * 4;                        // pair index base within head
    uint16_t* p = ptr + (size_t)row * Dn + c * 8;
    u16x8 v = *(u16x8*)p;
    u16x8 o;
    #pragma unroll
    for (int j = 0; j < 4; j++) {
        float c_ = ct[s * 32 + i0 + j];
        float s_ = st[s * 32 + i0 + j];
        float x1 = bf2f(v[2 * j]);
        float x2 = bf2f(v[2 * j + 1]);
        o[2 * j]     = f2bf_bits((x1 * c_ - x2 * s_) * scale);
        o[2 * j + 1] = f2bf_bits((x2 * c_ + x1 * s_) * scale);
    }
    *(u16x8*)p = o;
}

// ---------------- GEMM: C[M=8192, N=1024] = A[8192,1024] @ Bt[n][k]^T ----------------
// EPI: 0 = bf16 row-major, 1 = bf16 transposed Vt(B,H,DH,S), 2 = fp32 row-major
template<int EPI>
__global__ __launch_bounds__(256, 2)
void gemm_k(const uint16_t* __restrict__ A, const uint16_t* __restrict__ Bt,
            void* __restrict__ C) {
    __shared__ uint16_t lA[128 * 32];
    __shared__ uint16_t lB[128 * 32];
    const int t = threadIdx.x;
    const int lane = t & 63, wid = t >> 6;
    const int wm = wid >> 1, wn = wid & 1;
    const int gm0 = blockIdx.x * 128, gn0 = blockIdx.y * 128;
    const int l15 = lane & 15, l4 = lane >> 4;

    f32x4 acc[4][4];
    #pragma unroll
    for (int i = 0; i < 4; i++)
        #pragma unroll
        for (int j = 0; j < 4; j++) acc[i][j] = f32x4{0.f, 0.f, 0.f, 0.f};

    const int srow = lane >> 2;          // 0..15
    const int scol = (lane & 3) * 8;     // element col

    for (int k0 = 0; k0 < Dn; k0 += 32) {
        __syncthreads();
        #pragma unroll
        for (int i = 0; i < 2; i++) {
            int row = wid * 32 + i * 16 + srow;
            load16_to_lds(A  + (size_t)(gm0 + row) * Dn + k0 + scol, &lA[row * 32 + scol]);
            load16_to_lds(Bt + (size_t)(gn0 + row) * Dn + k0 + scol, &lB[row * 32 + scol]);
        }
        __syncthreads();
        bf16x8 aF[4], bF[4];
        #pragma unroll
        for (int mi = 0; mi < 4; mi++)
            aF[mi] = *(const bf16x8*)&lA[(wm * 64 + mi * 16 + l15) * 32 + l4 * 8];
        #pragma unroll
        for (int ni = 0; ni < 4; ni++)
            bF[ni] = *(const bf16x8*)&lB[(wn * 64 + ni * 16 + l15) * 32 + l4 * 8];
        #pragma unroll
        for (int mi = 0; mi < 4; mi++)
            #pragma unroll
            for (int ni = 0; ni < 4; ni++)
                acc[mi][ni] = mfma16(aF[mi], bF[ni], acc[mi][ni]);
    }

    if constexpr (EPI == 0) {
        uint16_t* Cb = (uint16_t*)C;
        #pragma unroll
        for (int mi = 0; mi < 4; mi++)
            #pragma unroll
            for (int ni = 0; ni < 4; ni++)
                #pragma unroll
                for (int r = 0; r < 4; r++) {
                    int row = gm0 + wm * 64 + mi * 16 + l4 * 4 + r;
                    int col = gn0 + wn * 64 + ni * 16 + l15;
                    Cb[(size_t)row * Dn + col] = f2bf_bits(acc[mi][ni][r]);
                }
    } else if constexpr (EPI == 1) {
        uint16_t* Vt = (uint16_t*)C;
        #pragma unroll
        for (int mi = 0; mi < 4; mi++)
            #pragma unroll
            for (int ni = 0; ni < 4; ni++) {
                int n  = gn0 + wn * 64 + ni * 16 + l15;
                int h  = n >> 6, dh = n & 63;
                int m0 = gm0 + wm * 64 + mi * 16 + l4 * 4;
                int b  = m0 >> 11, s = m0 & (Sn - 1);
                u16x4 pk;
                #pragma unroll
                for (int r = 0; r < 4; r++) pk[r] = f2bf_bits(acc[mi][ni][r]);
                *(u16x4*)&Vt[(((size_t)(b * Hn + h)) * DHn + dh) * Sn + s] = pk;
            }
    } else {
        float* Cf = (float*)C;
        #pragma unroll
        for (int mi = 0; mi < 4; mi++)
            #pragma unroll
            for (int ni = 0; ni < 4; ni++)
                #pragma unroll
                for (int r = 0; r < 4; r++) {
                    int row = gm0 + wm * 64 + mi * 16 + l4 * 4 + r;
                    int col = gn0 + wn * 64 + ni * 16 + l15;
                    Cf[(size_t)row * Dn + col] = acc[mi][ni][r];
                }
    }
}

// ---------------- flash attention v4 (causal, balanced tile-pairs) ----------------
// grid (16, B*H) blocks of 256. Wave w of block x owns q-tile pair {j, 63-j},
// j = 4x + w, processed sequentially: (j+1) + (64-j) = 65 steps for EVERY wave
// -> perfect static balance at wave/SIMD/CU level regardless of dispatch mapping.
// Per pass: 32 q rows (2 frags), KVBLK=32, register-pipelined K prefetch,
// V issued early. Scores: S^T = mfma(K, Q) -> lane q=l15, kv=(l>>4)*4+r.
// Softmax: per-lane deferred max (cross-lane shfl only when THR=8 exceeded),
// per-lane partial l reduced once in epilogue. PV: O^T = mfma(V^T, P^T), 16x16x16.
// Q pre-scaled by 1/8 in rope_apply_k.
__global__ __launch_bounds__(256, 4)
void attn_k(const uint16_t* __restrict__ Q, const uint16_t* __restrict__ K,
            const uint16_t* __restrict__ Vt, uint16_t* __restrict__ O) {
    const int t = threadIdx.x, lane = t & 63, wid = t >> 6;
    const int bh = blockIdx.y, b = bh >> 4, h = bh & 15;
    const int j = blockIdx.x * 4 + wid;           // 0..63
    const int l15 = lane & 15, l4 = lane >> 4;

    const uint16_t* Kbase = K + ((size_t)(b * Sn)) * Dn + h * DHn;
    const uint16_t* Vbase = Vt + ((size_t)bh) * DHn * Sn;

    for (int pass = 0; pass < 2; pass++) {
        const int tile = pass ? (63 - j) : j;
        const int q0w = tile * 32;
        const int nsteps = tile + 1;

        // hoist Q fragments (B-operand of scores MFMA)
        bf16x8 qf0[2], qf1[2];
        #pragma unroll
        for (int f = 0; f < 2; f++) {
            const uint16_t* Qp = Q + ((size_t)(b * Sn + q0w + f * 16 + l15)) * Dn + h * DHn + l4 * 8;
            qf0[f] = *(const bf16x8*)Qp;
            qf1[f] = *(const bf16x8*)(Qp + 32);
        }

        f32x4 acc[2][4];   // [frag][db]: O^T, col q=l15, row dh = db*16 + l4*4 + r
        #pragma unroll
        for (int f = 0; f < 2; f++)
            #pragma unroll
            for (int db = 0; db < 4; db++) acc[f][db] = f32x4{0.f, 0.f, 0.f, 0.f};
        float m_[2] = {-INFINITY, -INFINITY};
        float lp[2] = {0.f, 0.f};                 // per-lane partial sums

        // preload K step 0
        bf16x8 kf[2][2];
        #pragma unroll
        for (int c = 0; c < 2; c++) {
            const uint16_t* Kp = Kbase + (size_t)(c * 16 + l15) * Dn + l4 * 8;
            kf[c][0] = *(const bf16x8*)Kp;
            kf[c][1] = *(const bf16x8*)(Kp + 32);
        }

        for (int s = 0; s < nsteps; s++) {
            const int k0 = s * 32;
            // V for current step (issued early; consumed after softmax)
            u16x4 vt4[2][4];
            #pragma unroll
            for (int c = 0; c < 2; c++)
                #pragma unroll
                for (int db = 0; db < 4; db++)
                    vt4[c][db] = *(const u16x4*)&Vbase[(size_t)(db * 16 + l15) * Sn + k0 + c * 16 + l4 * 4];

            // scores (consume kf)
            f32x4 st[2][2];
            #pragma unroll
            for (int f = 0; f < 2; f++)
                #pragma unroll
                for (int c = 0; c < 2; c++) {
                    f32x4 z = mfma16(kf[c][0], qf0[f], f32x4{0.f, 0.f, 0.f, 0.f});
                    st[f][c] = mfma16(kf[c][1], qf1[f], z);
                }

            // prefetch next step's K into the now-dead kf regs (clamped, no branch)
            {
                const int k1 = (k0 + 32 < Sn) ? (k0 + 32) : (Sn - 32);
                #pragma unroll
                for (int c = 0; c < 2; c++) {
                    const uint16_t* Kp = Kbase + (size_t)(k1 + c * 16 + l15) * Dn + l4 * 8;
                    kf[c][0] = *(const bf16x8*)Kp;
                    kf[c][1] = *(const bf16x8*)(Kp + 32);
                }
            }

            // causal mask — only the last step touches the diagonal
            if (s == nsteps - 1) {
                #pragma unroll
                for (int f = 0; f < 2; f++) {
                    const int qrow = q0w + f * 16 + l15;
                    #pragma unroll
                    for (int c = 0; c < 2; c++) {
                        const int kvb = k0 + c * 16 + l4 * 4;
                        #pragma unroll
                        for (int r = 0; r < 4; r++)
                            if (kvb + r > qrow) st[f][c][r] = -INFINITY;
                    }
                }
            }

            // softmax + PV per frag
            #pragma unroll
            for (int f = 0; f < 2; f++) {
                f32x4 s0 = st[f][0], s1 = st[f][1];
                // per-lane max over this lane's 8 slots
                float mxl = fmaxf(fmaxf(fmaxf(s0[0], s0[1]), fmaxf(s0[2], s0[3])),
                                  fmaxf(fmaxf(s1[0], s1[1]), fmaxf(s1[2], s1[3])));
                // deferred cross-lane max: shuffle+rescale only when THR exceeded
                if (!__all(mxl <= m_[f] + 8.0f)) {
                    float mx = mxl;
                    mx = fmaxf(mx, __shfl_xor(mx, 16));
                    mx = fmaxf(mx, __shfl_xor(mx, 32));
                    float mnew = fmaxf(m_[f], mx);
                    float sf = __expf(m_[f] - mnew);
                    m_[f] = mnew;
                    lp[f] *= sf;
                    #pragma unroll
                    for (int db = 0; db < 4; db++) {
                        acc[f][db][0] *= sf; acc[f][db][1] *= sf;
                        acc[f][db][2] *= sf; acc[f][db][3] *= sf;
                    }
                }
                float p0 = __expf(s0[0] - m_[f]);
                float p1 = __expf(s0[1] - m_[f]);
                float p2 = __expf(s0[2] - m_[f]);
                float p3 = __expf(s0[3] - m_[f]);
                float p4 = __expf(s1[0] - m_[f]);
                float p5 = __expf(s1[1] - m_[f]);
                float p6 = __expf(s1[2] - m_[f]);
                float p7 = __expf(s1[3] - m_[f]);
                lp[f] += ((p0 + p1) + (p2 + p3)) + ((p4 + p5) + (p6 + p7));
                union { u16x4 v; uint32_t w[2]; } pf0, pf1;
                pf0.w[0] = cvt2bf(p0, p1); pf0.w[1] = cvt2bf(p2, p3);
                pf1.w[0] = cvt2bf(p4, p5); pf1.w[1] = cvt2bf(p6, p7);
                #pragma unroll
                for (int db = 0; db < 4; db++)
                    acc[f][db] = mfma16k16(vt4[0][db], pf0.v, acc[f][db]);
                #pragma unroll
                for (int db = 0; db < 4; db++)
                    acc[f][db] = mfma16k16(vt4[1][db], pf1.v, acc[f][db]);
            }
        }

        // epilogue: cross-lane l reduce, normalize, write O[q][h*64+dh]
        #pragma unroll
        for (int f = 0; f < 2; f++) {
            float lt = lp[f];
            lt += __shfl_xor(lt, 16);
            lt += __shfl_xor(lt, 32);
            float inv = 1.0f / lt;
            const int qrow = q0w + f * 16 + l15;
            uint16_t* Op = O + ((size_t)(b * Sn + qrow)) * Dn + h * DHn;
            #pragma unroll
            for (int db = 0; db < 4; db++) {
                u16x4 o4;
                #pragma unroll
                for (int r = 0; r < 4; r++) o4[r] = f2bf_bits(acc[f][db][r] * inv);
                *(u16x4*)&Op[db * 16 + l4 * 4] = o4;
            }
        }
    }
}

// ---------------- launcher ----------------
extern "C" void kernel_launch(void* const* d_in, const int* in_sizes, int n_in,
                              void* d_out, int out_size, void* d_ws, size_t ws_size,
                              hipStream_t stream) {
    const float* x  = (const float*)d_in[0];
    const float* Wq = (const float*)d_in[1];
    const float* Wk = (const float*)d_in[2];
    const float* Wv = (const float*)d_in[3];
    const float* Wo = (const float*)d_in[4];

    char* ws = (char*)d_ws;
    uint16_t* xb   = (uint16_t*)(ws);                       // 16 MB
    uint16_t* wt   = (uint16_t*)(ws + 16777216);            // 8 MB  (4 x 1M elems)
    uint16_t* q    = (uint16_t*)(ws + 25165824);            // 16 MB
    uint16_t* k    = (uint16_t*)(ws + 41943040);            // 16 MB
    uint16_t* vt   = (uint16_t*)(ws + 58720256);            // 16 MB
    uint16_t* attn = (uint16_t*)(ws + 75497472);            // 16 MB
    float*    ct   = (float*)(ws + 92274688);               // 256 KB
    float*    st   = (float*)(ws + 92536832);               // 256 KB

    cast_x_k<<<8192, 256, 0, stream>>>(x, xb);
    transpose_cast_w<<<dim3(32, 32, 4), dim3(32, 32), 0, stream>>>(Wq, Wk, Wv, Wo, wt);
    rope_table_k<<<256, 256, 0, stream>>>(ct, st);

    gemm_k<0><<<dim3(64, 8), 256, 0, stream>>>(xb, wt + 0 * Dn * Dn, q);
    gemm_k<0><<<dim3(64, 8), 256, 0, stream>>>(xb, wt + 1 * Dn * Dn, k);
    gemm_k<1><<<dim3(64, 8), 256, 0, stream>>>(xb, wt + 2 * Dn * Dn, vt);

    rope_apply_k<<<dim3(4096, 2), 256, 0, stream>>>(q, k, ct, st);

    attn_k<<<dim3(16, Bn * Hn), 256, 0, stream>>>(q, k, vt, attn);

    gemm_k<2><<<dim3(64, 8), 256, 0, stream>>>(attn, wt + 3 * Dn * Dn, (float*)d_out);
}

// Round 6
// 291.846 us; speedup vs baseline: 1.9474x; 1.9474x over previous
//
#include <hip/hip_runtime.h>
#include <hip/hip_bf16.h>
#include <stdint.h>

#define DEV __device__ __forceinline__

// ---- constants for this problem ----
#define Bn 4
#define Sn 2048
#define Dn 1024
#define Hn 16
#define DHn 64
#define Mn (Bn*Sn)   // 8192

typedef __attribute__((ext_vector_type(8))) __bf16   bf16x8;
typedef __attribute__((ext_vector_type(4))) __bf16   bf16x4;
typedef __attribute__((ext_vector_type(4))) float    f32x4;
typedef __attribute__((ext_vector_type(8))) uint16_t u16x8;
typedef __attribute__((ext_vector_type(4))) uint16_t u16x4;
typedef __attribute__((ext_vector_type(4))) short    s16x4;

DEV uint16_t f2bf_bits(float f) {
    union { float f; uint32_t u; } v; v.f = f;
    uint32_t r = v.u + 0x7FFFu + ((v.u >> 16) & 1u);
    return (uint16_t)(r >> 16);
}
DEV float bf2f(uint16_t b) {
    union { uint32_t u; float f; } v; v.u = ((uint32_t)b) << 16;
    return v.f;
}

// pair float->bf16 via hardware v_cvt_pk_bf16_f32
DEV uint32_t cvt2bf(float a, float b) {
    __hip_bfloat162 h2 = __float22bfloat162_rn(float2{a, b});
    uint32_t u; __builtin_memcpy(&u, &h2, 4); return u;
}

DEV void load16_to_lds(const void* gsrc, void* ldst) {
    __builtin_amdgcn_global_load_lds(
        (const __attribute__((address_space(1))) uint32_t*)gsrc,
        (__attribute__((address_space(3))) uint32_t*)ldst,
        16, 0, 0);
}

DEV f32x4 mfma16(bf16x8 a, bf16x8 b, f32x4 c) {
    return __builtin_amdgcn_mfma_f32_16x16x32_bf16(a, b, c, 0, 0, 0);
}

// 16x16x16 bf16 MFMA (A,B = 4 bf16 per lane)
DEV f32x4 mfma16k16(u16x4 a_bits, u16x4 b_bits, f32x4 c) {
#if __has_builtin(__builtin_amdgcn_mfma_f32_16x16x16_bf16)
    bf16x4 a, b;
    __builtin_memcpy(&a, &a_bits, 8);
    __builtin_memcpy(&b, &b_bits, 8);
    return __builtin_amdgcn_mfma_f32_16x16x16_bf16(a, b, c, 0, 0, 0);
#else
    s16x4 a, b;
    __builtin_memcpy(&a, &a_bits, 8);
    __builtin_memcpy(&b, &b_bits, 8);
    return __builtin_amdgcn_mfma_f32_16x16x16bf16_1k(a, b, c, 0, 0, 0);
#endif
}

// ---------------- elementwise: cast x fp32 -> bf16 ----------------
__global__ void cast_x_k(const float* __restrict__ x, uint16_t* __restrict__ xb) {
    size_t i = ((size_t)blockIdx.x * 256 + threadIdx.x) * 4;
    f32x4 v = *(const f32x4*)(x + i);
    u16x4 o;
    #pragma unroll
    for (int j = 0; j < 4; j++) o[j] = f2bf_bits(v[j]);
    *(u16x4*)(xb + i) = o;
}

// ---------------- transpose+cast weights: Wt[n][k] = bf16(W[k][n]) ----------------
__global__ void transpose_cast_w(const float* __restrict__ W0, const float* __restrict__ W1,
                                 const float* __restrict__ W2, const float* __restrict__ W3,
                                 uint16_t* __restrict__ WtAll) {
    __shared__ float tile[32][33];
    const float* Ws[4] = {W0, W1, W2, W3};
    const float* W = Ws[blockIdx.z];
    uint16_t* Wt = WtAll + (size_t)blockIdx.z * Dn * Dn;
    int tx = threadIdx.x, ty = threadIdx.y;
    int n0 = blockIdx.x * 32, k0 = blockIdx.y * 32;
    tile[ty][tx] = W[(size_t)(k0 + ty) * Dn + n0 + tx];
    __syncthreads();
    Wt[(size_t)(n0 + ty) * Dn + k0 + tx] = f2bf_bits(tile[tx][ty]);
}

// ---------------- rope table ----------------
__global__ void rope_table_k(float* __restrict__ ct, float* __restrict__ st) {
    int i = blockIdx.x * 256 + threadIdx.x;   // 0..65535
    int s = i >> 5, f = i & 31;
    float inv = powf(10000.0f, -(float)f / 32.0f);
    float a = (float)s * inv;
    ct[i] = cosf(a);
    st[i] = sinf(a);
}

// ---------------- rope apply (in-place on Q or K); Q also scaled by 1/8 ----------------
__global__ void rope_apply_k(uint16_t* __restrict__ Q, uint16_t* __restrict__ Kt,
                             const float* __restrict__ ct, const float* __restrict__ st) {
    int idx = blockIdx.x * 256 + threadIdx.x;   // 0..1048575 (8192 rows * 128 chunks)
    uint16_t* ptr = (blockIdx.y == 0) ? Q : Kt;
    const float scale = (blockIdx.y == 0) ? 0.125f : 1.0f;
    int row = idx >> 7, c = idx & 127;
    int s = row & (Sn - 1);
    int i0 = (c & 7) * 4;                        // pair index base within head
    uint16_t* p = ptr + (size_t)row * Dn + c * 8;
    u16x8 v = *(u16x8*)p;
    u16x8 o;
    #pragma unroll
    for (int j = 0; j < 4; j++) {
        float c_ = ct[s * 32 + i0 + j];
        float s_ = st[s * 32 + i0 + j];
        float x1 = bf2f(v[2 * j]);
        float x2 = bf2f(v[2 * j + 1]);
        o[2 * j]     = f2bf_bits((x1 * c_ - x2 * s_) * scale);
        o[2 * j + 1] = f2bf_bits((x2 * c_ + x1 * s_) * scale);
    }
    *(u16x8*)p = o;
}

// ---------------- GEMM: C[M=8192, N=1024] = A[8192,1024] @ Bt[n][k]^T ----------------
// EPI: 0 = bf16 row-major, 1 = bf16 transposed Vt(B,H,DH,S), 2 = fp32 row-major
template<int EPI>
__global__ __launch_bounds__(256, 2)
void gemm_k(const uint16_t* __restrict__ A, const uint16_t* __restrict__ Bt,
            void* __restrict__ C) {
    __shared__ uint16_t lA[128 * 32];
    __shared__ uint16_t lB[128 * 32];
    const int t = threadIdx.x;
    const int lane = t & 63, wid = t >> 6;
    const int wm = wid >> 1, wn = wid & 1;
    const int gm0 = blockIdx.x * 128, gn0 = blockIdx.y * 128;
    const int l15 = lane & 15, l4 = lane >> 4;

    f32x4 acc[4][4];
    #pragma unroll
    for (int i = 0; i < 4; i++)
        #pragma unroll
        for (int j = 0; j < 4; j++) acc[i][j] = f32x4{0.f, 0.f, 0.f, 0.f};

    const int srow = lane >> 2;          // 0..15
    const int scol = (lane & 3) * 8;     // element col

    for (int k0 = 0; k0 < Dn; k0 += 32) {
        __syncthreads();
        #pragma unroll
        for (int i = 0; i < 2; i++) {
            int row = wid * 32 + i * 16 + srow;
            load16_to_lds(A  + (size_t)(gm0 + row) * Dn + k0 + scol, &lA[row * 32 + scol]);
            load16_to_lds(Bt + (size_t)(gn0 + row) * Dn + k0 + scol, &lB[row * 32 + scol]);
        }
        __syncthreads();
        bf16x8 aF[4], bF[4];
        #pragma unroll
        for (int mi = 0; mi < 4; mi++)
            aF[mi] = *(const bf16x8*)&lA[(wm * 64 + mi * 16 + l15) * 32 + l4 * 8];
        #pragma unroll
        for (int ni = 0; ni < 4; ni++)
            bF[ni] = *(const bf16x8*)&lB[(wn * 64 + ni * 16 + l15) * 32 + l4 * 8];
        #pragma unroll
        for (int mi = 0; mi < 4; mi++)
            #pragma unroll
            for (int ni = 0; ni < 4; ni++)
                acc[mi][ni] = mfma16(aF[mi], bF[ni], acc[mi][ni]);
    }

    if constexpr (EPI == 0) {
        uint16_t* Cb = (uint16_t*)C;
        #pragma unroll
        for (int mi = 0; mi < 4; mi++)
            #pragma unroll
            for (int ni = 0; ni < 4; ni++)
                #pragma unroll
                for (int r = 0; r < 4; r++) {
                    int row = gm0 + wm * 64 + mi * 16 + l4 * 4 + r;
                    int col = gn0 + wn * 64 + ni * 16 + l15;
                    Cb[(size_t)row * Dn + col] = f2bf_bits(acc[mi][ni][r]);
                }
    } else if constexpr (EPI == 1) {
        uint16_t* Vt = (uint16_t*)C;
        #pragma unroll
        for (int mi = 0; mi < 4; mi++)
            #pragma unroll
            for (int ni = 0; ni < 4; ni++) {
                int n  = gn0 + wn * 64 + ni * 16 + l15;
                int h  = n >> 6, dh = n & 63;
                int m0 = gm0 + wm * 64 + mi * 16 + l4 * 4;
                int b  = m0 >> 11, s = m0 & (Sn - 1);
                u16x4 pk;
                #pragma unroll
                for (int r = 0; r < 4; r++) pk[r] = f2bf_bits(acc[mi][ni][r]);
                *(u16x4*)&Vt[(((size_t)(b * Hn + h)) * DHn + dh) * Sn + s] = pk;
            }
    } else {
        float* Cf = (float*)C;
        #pragma unroll
        for (int mi = 0; mi < 4; mi++)
            #pragma unroll
            for (int ni = 0; ni < 4; ni++)
                #pragma unroll
                for (int r = 0; r < 4; r++) {
                    int row = gm0 + wm * 64 + mi * 16 + l4 * 4 + r;
                    int col = gn0 + wn * 64 + ni * 16 + l15;
                    Cf[(size_t)row * Dn + col] = acc[mi][ni][r];
                }
    }
}

// ---------------- flash attention v5 (causal, LDS-staged K/V, balanced pairs) ----------------
// grid (8, B*H) blocks of 256 (4 waves). Block bx processes tile pair {bx, 15-bx}
// (128 q rows each) sequentially: (2bx+2)+(32-2bx) = 34 kv-blocks for EVERY block.
// Per kv-block (64 kv): K(64x64) and V^T(64x64) staged in double-buffered LDS via
// global_load_lds w=16 (2-phase: STAGE(next) -> compute(cur) -> barrier). XOR swizzle
// byte^=((row&7)<<4) applied on the global SOURCE during staging and on ds_read
// (rule 21: both-sides involution) to kill the stride-128B bank conflict.
// Scores: S^T = mfma(K, Q) -> lane q=l15, kv=(l>>4)*4+r. Softmax in-register with
// per-lane deferred max (THR=8), per-lane partial l reduced once in epilogue.
// PV: O^T = mfma(V^T, P^T) 16x16x16. Q pre-scaled by 1/8 in rope_apply_k.
__global__ __launch_bounds__(256, 2)
void attn_k(const uint16_t* __restrict__ Q, const uint16_t* __restrict__ K,
            const uint16_t* __restrict__ Vt, uint16_t* __restrict__ O) {
    __shared__ uint16_t lK[2][64 * 64];
    __shared__ uint16_t lV[2][64 * 64];
    const int t = threadIdx.x, lane = t & 63, wid = t >> 6;
    const int bh = blockIdx.y, b = bh >> 4, h = bh & 15;
    const int l15 = lane & 15, l4 = lane >> 4;

    const uint16_t* Kbase = K + ((size_t)(b * Sn)) * Dn + h * DHn;
    const uint16_t* Vbase = Vt + ((size_t)bh) * DHn * Sn;

    // staging geometry: dest linear elems (t + it*256)*8; row=(t>>3)+it*32,
    // src col (elems) pre-swizzled: (t&7)*8 ^ ((row&7)*8)
    const int srow = t >> 3;                          // 0..31 (it adds 32)
    const int scol = ((t & 7) * 8) ^ ((srow & 7) * 8);

    for (int pass = 0; pass < 2; pass++) {
        const int T = pass ? (15 - (int)blockIdx.x) : (int)blockIdx.x;
        const int q0w = T * 128 + wid * 32;
        const int nkb = 2 * T + 2;

        // hoist Q fragments (B-operand of scores MFMA)
        bf16x8 qf0[2], qf1[2];
        #pragma unroll
        for (int f = 0; f < 2; f++) {
            const uint16_t* Qp = Q + ((size_t)(b * Sn + q0w + f * 16 + l15)) * Dn + h * DHn + l4 * 8;
            qf0[f] = *(const bf16x8*)Qp;
            qf1[f] = *(const bf16x8*)(Qp + 32);
        }

        f32x4 acc[2][4];
        #pragma unroll
        for (int f = 0; f < 2; f++)
            #pragma unroll
            for (int db = 0; db < 4; db++) acc[f][db] = f32x4{0.f, 0.f, 0.f, 0.f};
        float m_[2] = {-INFINITY, -INFINITY};
        float lp[2] = {0.f, 0.f};

        // prologue: stage kv-block 0 into buffer 0
        #pragma unroll
        for (int it = 0; it < 2; it++) {
            const int row = srow + it * 32;
            load16_to_lds(Kbase + (size_t)row * Dn + scol, &lK[0][(size_t)(t + it * 256) * 8]);
            load16_to_lds(Vbase + (size_t)row * Sn + scol, &lV[0][(size_t)(t + it * 256) * 8]);
        }
        __syncthreads();

        int cur = 0;
        for (int kb = 0; kb < nkb; kb++) {
            // stage next kv-block into the other buffer (async, drained at barrier)
            if (kb + 1 < nkb) {
                const int kv1 = (kb + 1) * 64;
                #pragma unroll
                for (int it = 0; it < 2; it++) {
                    const int row = srow + it * 32;
                    load16_to_lds(Kbase + (size_t)(kv1 + row) * Dn + scol,
                                  &lK[cur ^ 1][(size_t)(t + it * 256) * 8]);
                    load16_to_lds(Vbase + (size_t)row * Sn + kv1 + scol,
                                  &lV[cur ^ 1][(size_t)(t + it * 256) * 8]);
                }
            }

            // ---- compute on buffer cur ----
            // K frags: rows kv=c*16+l15, col halves (shared by both q-frags)
            bf16x8 kf[4][2];
            #pragma unroll
            for (int c = 0; c < 4; c++) {
                const int row = c * 16 + l15;
                const int base = row * 64;
                const int off0 = (l4 * 8) ^ ((l15 & 7) * 8);
                const int off1 = (l4 * 8 + 32) ^ ((l15 & 7) * 8);
                kf[c][0] = *(const bf16x8*)&lK[cur][base + off0];
                kf[c][1] = *(const bf16x8*)&lK[cur][base + off1];
            }
            // V^T frags: rows dh=db*16+l15, kv chunks (shared by both q-frags)
            u16x4 vt4[4][4];
            #pragma unroll
            for (int db = 0; db < 4; db++) {
                const int base = (db * 16 + l15) * 64;
                const int sw = (l15 & 7) * 8;
                #pragma unroll
                for (int cc = 0; cc < 4; cc++)
                    vt4[cc][db] = *(const u16x4*)&lV[cur][base + ((cc * 16 + l4 * 4) ^ sw)];
            }

            // scores
            f32x4 st[2][4];
            #pragma unroll
            for (int f = 0; f < 2; f++)
                #pragma unroll
                for (int c = 0; c < 4; c++) {
                    f32x4 z = mfma16(kf[c][0], qf0[f], f32x4{0.f, 0.f, 0.f, 0.f});
                    st[f][c] = mfma16(kf[c][1], qf1[f], z);
                }

            // causal mask (only kv-blocks that cross the wave's diagonal)
            if (kb * 64 + 63 > q0w) {
                #pragma unroll
                for (int f = 0; f < 2; f++) {
                    const int qrow = q0w + f * 16 + l15;
                    #pragma unroll
                    for (int c = 0; c < 4; c++) {
                        const int kvb = kb * 64 + c * 16 + l4 * 4;
                        #pragma unroll
                        for (int r = 0; r < 4; r++)
                            if (kvb + r > qrow) st[f][c][r] = -INFINITY;
                    }
                }
            }

            // softmax + PV per frag
            #pragma unroll
            for (int f = 0; f < 2; f++) {
                float mxl = -INFINITY;
                #pragma unroll
                for (int c = 0; c < 4; c++)
                    mxl = fmaxf(mxl, fmaxf(fmaxf(st[f][c][0], st[f][c][1]),
                                           fmaxf(st[f][c][2], st[f][c][3])));
                if (!__all(mxl <= m_[f] + 8.0f)) {
                    float mx = mxl;
                    mx = fmaxf(mx, __shfl_xor(mx, 16));
                    mx = fmaxf(mx, __shfl_xor(mx, 32));
                    float mnew = fmaxf(m_[f], mx);
                    float sf = __expf(m_[f] - mnew);
                    m_[f] = mnew;
                    lp[f] *= sf;
                    #pragma unroll
                    for (int db = 0; db < 4; db++) {
                        acc[f][db][0] *= sf; acc[f][db][1] *= sf;
                        acc[f][db][2] *= sf; acc[f][db][3] *= sf;
                    }
                }
                #pragma unroll
                for (int c = 0; c < 4; c++) {
                    float p0 = __expf(st[f][c][0] - m_[f]);
                    float p1 = __expf(st[f][c][1] - m_[f]);
                    float p2 = __expf(st[f][c][2] - m_[f]);
                    float p3 = __expf(st[f][c][3] - m_[f]);
                    lp[f] += (p0 + p1) + (p2 + p3);
                    union { u16x4 v; uint32_t w[2]; } pf;
                    pf.w[0] = cvt2bf(p0, p1);
                    pf.w[1] = cvt2bf(p2, p3);
                    #pragma unroll
                    for (int db = 0; db < 4; db++)
                        acc[f][db] = mfma16k16(vt4[c][db], pf.v, acc[f][db]);
                }
            }

            __syncthreads();   // drains staged loads (vmcnt) + all waves done with cur
            cur ^= 1;
        }

        // epilogue: cross-lane l reduce, normalize, write O[q][h*64+dh]
        #pragma unroll
        for (int f = 0; f < 2; f++) {
            float lt = lp[f];
            lt += __shfl_xor(lt, 16);
            lt += __shfl_xor(lt, 32);
            float inv = 1.0f / lt;
            const int qrow = q0w + f * 16 + l15;
            uint16_t* Op = O + ((size_t)(b * Sn + qrow)) * Dn + h * DHn;
            #pragma unroll
            for (int db = 0; db < 4; db++) {
                u16x4 o4;
                #pragma unroll
                for (int r = 0; r < 4; r++) o4[r] = f2bf_bits(acc[f][db][r] * inv);
                *(u16x4*)&Op[db * 16 + l4 * 4] = o4;
            }
        }
    }
}

// ---------------- launcher ----------------
extern "C" void kernel_launch(void* const* d_in, const int* in_sizes, int n_in,
                              void* d_out, int out_size, void* d_ws, size_t ws_size,
                              hipStream_t stream) {
    const float* x  = (const float*)d_in[0];
    const float* Wq = (const float*)d_in[1];
    const float* Wk = (const float*)d_in[2];
    const float* Wv = (const float*)d_in[3];
    const float* Wo = (const float*)d_in[4];

    char* ws = (char*)d_ws;
    uint16_t* xb   = (uint16_t*)(ws);                       // 16 MB
    uint16_t* wt   = (uint16_t*)(ws + 16777216);            // 8 MB  (4 x 1M elems)
    uint16_t* q    = (uint16_t*)(ws + 25165824);            // 16 MB
    uint16_t* k    = (uint16_t*)(ws + 41943040);            // 16 MB
    uint16_t* vt   = (uint16_t*)(ws + 58720256);            // 16 MB
    uint16_t* attn = (uint16_t*)(ws + 75497472);            // 16 MB
    float*    ct   = (float*)(ws + 92274688);               // 256 KB
    float*    st   = (float*)(ws + 92536832);               // 256 KB

    cast_x_k<<<8192, 256, 0, stream>>>(x, xb);
    transpose_cast_w<<<dim3(32, 32, 4), dim3(32, 32), 0, stream>>>(Wq, Wk, Wv, Wo, wt);
    rope_table_k<<<256, 256, 0, stream>>>(ct, st);

    gemm_k<0><<<dim3(64, 8), 256, 0, stream>>>(xb, wt + 0 * Dn * Dn, q);
    gemm_k<0><<<dim3(64, 8), 256, 0, stream>>>(xb, wt + 1 * Dn * Dn, k);
    gemm_k<1><<<dim3(64, 8), 256, 0, stream>>>(xb, wt + 2 * Dn * Dn, vt);

    rope_apply_k<<<dim3(4096, 2), 256, 0, stream>>>(q, k, ct, st);

    attn_k<<<dim3(8, Bn * Hn), 256, 0, stream>>>(q, k, vt, attn);

    gemm_k<2><<<dim3(64, 8), 256, 0, stream>>>(attn, wt + 3 * Dn * Dn, (float*)d_out);
}

// Round 9
// 273.329 us; speedup vs baseline: 2.0794x; 1.0677x over previous
//
#include <hip/hip_runtime.h>
#include <hip/hip_bf16.h>
#include <stdint.h>

#define DEV __device__ __forceinline__

// ---- constants for this problem ----
#define Bn 4
#define Sn 2048
#define Dn 1024
#define Hn 16
#define DHn 64
#define Mn (Bn*Sn)   // 8192

typedef __attribute__((ext_vector_type(8))) __bf16   bf16x8;
typedef __attribute__((ext_vector_type(4))) __bf16   bf16x4;
typedef __attribute__((ext_vector_type(4))) float    f32x4;
typedef __attribute__((ext_vector_type(8))) uint16_t u16x8;
typedef __attribute__((ext_vector_type(4))) uint16_t u16x4;
typedef __attribute__((ext_vector_type(4))) short    s16x4;

DEV uint16_t f2bf_bits(float f) {
    union { float f; uint32_t u; } v; v.f = f;
    uint32_t r = v.u + 0x7FFFu + ((v.u >> 16) & 1u);
    return (uint16_t)(r >> 16);
}
DEV float bf2f(uint16_t b) {
    union { uint32_t u; float f; } v; v.u = ((uint32_t)b) << 16;
    return v.f;
}

// pair float->bf16 via hardware v_cvt_pk_bf16_f32
DEV uint32_t cvt2bf(float a, float b) {
    __hip_bfloat162 h2 = __float22bfloat162_rn(float2{a, b});
    uint32_t u; __builtin_memcpy(&u, &h2, 4); return u;
}

DEV void load16_to_lds(const void* gsrc, void* ldst) {
    __builtin_amdgcn_global_load_lds(
        (const __attribute__((address_space(1))) uint32_t*)gsrc,
        (__attribute__((address_space(3))) uint32_t*)ldst,
        16, 0, 0);
}

DEV f32x4 mfma16(bf16x8 a, bf16x8 b, f32x4 c) {
    return __builtin_amdgcn_mfma_f32_16x16x32_bf16(a, b, c, 0, 0, 0);
}

// 16x16x16 bf16 MFMA (A,B = 4 bf16 per lane)
DEV f32x4 mfma16k16(u16x4 a_bits, u16x4 b_bits, f32x4 c) {
#if __has_builtin(__builtin_amdgcn_mfma_f32_16x16x16_bf16)
    bf16x4 a, b;
    __builtin_memcpy(&a, &a_bits, 8);
    __builtin_memcpy(&b, &b_bits, 8);
    return __builtin_amdgcn_mfma_f32_16x16x16_bf16(a, b, c, 0, 0, 0);
#else
    s16x4 a, b;
    __builtin_memcpy(&a, &a_bits, 8);
    __builtin_memcpy(&b, &b_bits, 8);
    return __builtin_amdgcn_mfma_f32_16x16x16bf16_1k(a, b, c, 0, 0, 0);
#endif
}

// ---------------- elementwise: cast x fp32 -> bf16 ----------------
__global__ void cast_x_k(const float* __restrict__ x, uint16_t* __restrict__ xb) {
    size_t i = ((size_t)blockIdx.x * 256 + threadIdx.x) * 4;
    f32x4 v = *(const f32x4*)(x + i);
    u16x4 o;
    #pragma unroll
    for (int j = 0; j < 4; j++) o[j] = f2bf_bits(v[j]);
    *(u16x4*)(xb + i) = o;
}

// ---------------- transpose+cast weights: Wt[n][k] = bf16(W[k][n]) ----------------
__global__ void transpose_cast_w(const float* __restrict__ W0, const float* __restrict__ W1,
                                 const float* __restrict__ W2, const float* __restrict__ W3,
                                 uint16_t* __restrict__ WtAll) {
    __shared__ float tile[32][33];
    const float* Ws[4] = {W0, W1, W2, W3};
    const float* W = Ws[blockIdx.z];
    uint16_t* Wt = WtAll + (size_t)blockIdx.z * Dn * Dn;
    int tx = threadIdx.x, ty = threadIdx.y;
    int n0 = blockIdx.x * 32, k0 = blockIdx.y * 32;
    tile[ty][tx] = W[(size_t)(k0 + ty) * Dn + n0 + tx];
    __syncthreads();
    Wt[(size_t)(n0 + ty) * Dn + k0 + tx] = f2bf_bits(tile[tx][ty]);
}

// ---------------- rope table ----------------
__global__ void rope_table_k(float* __restrict__ ct, float* __restrict__ st) {
    int i = blockIdx.x * 256 + threadIdx.x;   // 0..65535
    int s = i >> 5, f = i & 31;
    float inv = powf(10000.0f, -(float)f / 32.0f);
    float a = (float)s * inv;
    ct[i] = cosf(a);
    st[i] = sinf(a);
}

// ---------------- rope apply (in-place on Q or K); Q also scaled by 1/8 ----------------
__global__ void rope_apply_k(uint16_t* __restrict__ Q, uint16_t* __restrict__ Kt,
                             const float* __restrict__ ct, const float* __restrict__ st) {
    int idx = blockIdx.x * 256 + threadIdx.x;   // 0..1048575 (8192 rows * 128 chunks)
    uint16_t* ptr = (blockIdx.y == 0) ? Q : Kt;
    const float scale = (blockIdx.y == 0) ? 0.125f : 1.0f;
    int row = idx >> 7, c = idx & 127;
    int s = row & (Sn - 1);
    int i0 = (c & 7) * 4;                        // pair index base within head
    uint16_t* p = ptr + (size_t)row * Dn + c * 8;
    u16x8 v = *(u16x8*)p;
    u16x8 o;
    #pragma unroll
    for (int j = 0; j < 4; j++) {
        float c_ = ct[s * 32 + i0 + j];
        float s_ = st[s * 32 + i0 + j];
        float x1 = bf2f(v[2 * j]);
        float x2 = bf2f(v[2 * j + 1]);
        o[2 * j]     = f2bf_bits((x1 * c_ - x2 * s_) * scale);
        o[2 * j + 1] = f2bf_bits((x2 * c_ + x1 * s_) * scale);
    }
    *(u16x8*)p = o;
}

// ---------------- fused QKV GEMM ----------------
// C[M=8192, N=3072] = A[8192,1024] @ BtAll[3072,1024]^T where BtAll = [Wq^T;Wk^T;Wv^T].
// grid (64, 24): by 0-7 -> Q (row-major bf16), 8-15 -> K (row-major bf16),
// 16-23 -> V written transposed as Vt(B,H,DH,S). 128x128 tile, BK=32, m97 structure.
__global__ __launch_bounds__(256, 3)
void gemm_qkv_k(const uint16_t* __restrict__ A, const uint16_t* __restrict__ BtAll,
                uint16_t* __restrict__ q, uint16_t* __restrict__ kk,
                uint16_t* __restrict__ vt) {
    __shared__ uint16_t lA[128 * 32];
    __shared__ uint16_t lB[128 * 32];
    const int t = threadIdx.x;
    const int lane = t & 63, wid = t >> 6;
    const int wm = wid >> 1, wn = wid & 1;
    const int gm0 = blockIdx.x * 128, gn0 = blockIdx.y * 128;   // gn0 in [0,3072)
    const int l15 = lane & 15, l4 = lane >> 4;

    f32x4 acc[4][4];
    #pragma unroll
    for (int i = 0; i < 4; i++)
        #pragma unroll
        for (int j = 0; j < 4; j++) acc[i][j] = f32x4{0.f, 0.f, 0.f, 0.f};

    const int srow = lane >> 2;          // 0..15
    const int scol = (lane & 3) * 8;     // element col

    for (int k0 = 0; k0 < Dn; k0 += 32) {
        __syncthreads();
        #pragma unroll
        for (int i = 0; i < 2; i++) {
            int row = wid * 32 + i * 16 + srow;
            load16_to_lds(A     + (size_t)(gm0 + row) * Dn + k0 + scol, &lA[row * 32 + scol]);
            load16_to_lds(BtAll + (size_t)(gn0 + row) * Dn + k0 + scol, &lB[row * 32 + scol]);
        }
        __syncthreads();
        bf16x8 aF[4], bF[4];
        #pragma unroll
        for (int mi = 0; mi < 4; mi++)
            aF[mi] = *(const bf16x8*)&lA[(wm * 64 + mi * 16 + l15) * 32 + l4 * 8];
        #pragma unroll
        for (int ni = 0; ni < 4; ni++)
            bF[ni] = *(const bf16x8*)&lB[(wn * 64 + ni * 16 + l15) * 32 + l4 * 8];
        #pragma unroll
        for (int mi = 0; mi < 4; mi++)
            #pragma unroll
            for (int ni = 0; ni < 4; ni++)
                acc[mi][ni] = mfma16(aF[mi], bF[ni], acc[mi][ni]);
    }

    const int mat = blockIdx.y >> 3;               // 0=Q, 1=K, 2=V
    if (mat < 2) {
        uint16_t* Cb = mat ? kk : q;
        const int ncol0 = (gn0 & 1023);
        #pragma unroll
        for (int mi = 0; mi < 4; mi++)
            #pragma unroll
            for (int ni = 0; ni < 4; ni++)
                #pragma unroll
                for (int r = 0; r < 4; r++) {
                    int row = gm0 + wm * 64 + mi * 16 + l4 * 4 + r;
                    int col = ncol0 + wn * 64 + ni * 16 + l15;
                    Cb[(size_t)row * Dn + col] = f2bf_bits(acc[mi][ni][r]);
                }
    } else {
        #pragma unroll
        for (int mi = 0; mi < 4; mi++)
            #pragma unroll
            for (int ni = 0; ni < 4; ni++) {
                int n  = (gn0 & 1023) + wn * 64 + ni * 16 + l15;
                int h  = n >> 6, dh = n & 63;
                int m0 = gm0 + wm * 64 + mi * 16 + l4 * 4;
                int b  = m0 >> 11, s = m0 & (Sn - 1);
                u16x4 pk;
                #pragma unroll
                for (int r = 0; r < 4; r++) pk[r] = f2bf_bits(acc[mi][ni][r]);
                *(u16x4*)&vt[(((size_t)(b * Hn + h)) * DHn + dh) * Sn + s] = pk;
            }
    }
}

// ---------------- output GEMM: out[8192,1024] fp32 = attn @ Wo^T ----------------
__global__ __launch_bounds__(256, 3)
void gemm_out_k(const uint16_t* __restrict__ A, const uint16_t* __restrict__ Bt,
                float* __restrict__ C) {
    __shared__ uint16_t lA[128 * 32];
    __shared__ uint16_t lB[128 * 32];
    const int t = threadIdx.x;
    const int lane = t & 63, wid = t >> 6;
    const int wm = wid >> 1, wn = wid & 1;
    const int gm0 = blockIdx.x * 128, gn0 = blockIdx.y * 128;
    const int l15 = lane & 15, l4 = lane >> 4;

    f32x4 acc[4][4];
    #pragma unroll
    for (int i = 0; i < 4; i++)
        #pragma unroll
        for (int j = 0; j < 4; j++) acc[i][j] = f32x4{0.f, 0.f, 0.f, 0.f};

    const int srow = lane >> 2;
    const int scol = (lane & 3) * 8;

    for (int k0 = 0; k0 < Dn; k0 += 32) {
        __syncthreads();
        #pragma unroll
        for (int i = 0; i < 2; i++) {
            int row = wid * 32 + i * 16 + srow;
            load16_to_lds(A  + (size_t)(gm0 + row) * Dn + k0 + scol, &lA[row * 32 + scol]);
            load16_to_lds(Bt + (size_t)(gn0 + row) * Dn + k0 + scol, &lB[row * 32 + scol]);
        }
        __syncthreads();
        bf16x8 aF[4], bF[4];
        #pragma unroll
        for (int mi = 0; mi < 4; mi++)
            aF[mi] = *(const bf16x8*)&lA[(wm * 64 + mi * 16 + l15) * 32 + l4 * 8];
        #pragma unroll
        for (int ni = 0; ni < 4; ni++)
            bF[ni] = *(const bf16x8*)&lB[(wn * 64 + ni * 16 + l15) * 32 + l4 * 8];
        #pragma unroll
        for (int mi = 0; mi < 4; mi++)
            #pragma unroll
            for (int ni = 0; ni < 4; ni++)
                acc[mi][ni] = mfma16(aF[mi], bF[ni], acc[mi][ni]);
    }

    #pragma unroll
    for (int mi = 0; mi < 4; mi++)
        #pragma unroll
        for (int ni = 0; ni < 4; ni++)
            #pragma unroll
            for (int r = 0; r < 4; r++) {
                int row = gm0 + wm * 64 + mi * 16 + l4 * 4 + r;
                int col = gn0 + wn * 64 + ni * 16 + l15;
                C[(size_t)row * Dn + col] = acc[mi][ni][r];
            }
}

// ---------------- flash attention v5 (causal, LDS-staged K/V, balanced pairs) ----------------
// grid (8, B*H) blocks of 256 (4 waves). Block bx processes tile pair {bx, 15-bx}
// (128 q rows each) sequentially: (2bx+2)+(32-2bx) = 34 kv-blocks for EVERY block.
// Per kv-block (64 kv): K(64x64) and V^T(64x64) staged in double-buffered LDS via
// global_load_lds w=16 (2-phase: STAGE(next) -> compute(cur) -> barrier). XOR swizzle
// byte^=((row&7)<<4) applied on the global SOURCE during staging and on ds_read
// (rule 21: both-sides involution) to kill the stride-128B bank conflict.
// Scores: S^T = mfma(K, Q) -> lane q=l15, kv=(l>>4)*4+r. Softmax in-register with
// per-lane deferred max (THR=8), per-lane partial l reduced once in epilogue.
// PV: O^T = mfma(V^T, P^T) 16x16x16. Q pre-scaled by 1/8 in rope_apply_k.
__global__ __launch_bounds__(256, 2)
void attn_k(const uint16_t* __restrict__ Q, const uint16_t* __restrict__ K,
            const uint16_t* __restrict__ Vt, uint16_t* __restrict__ O) {
    __shared__ uint16_t lK[2][64 * 64];
    __shared__ uint16_t lV[2][64 * 64];
    const int t = threadIdx.x, lane = t & 63, wid = t >> 6;
    const int bh = blockIdx.y, b = bh >> 4, h = bh & 15;
    const int l15 = lane & 15, l4 = lane >> 4;

    const uint16_t* Kbase = K + ((size_t)(b * Sn)) * Dn + h * DHn;
    const uint16_t* Vbase = Vt + ((size_t)bh) * DHn * Sn;

    const int srow = t >> 3;                          // 0..31 (it adds 32)
    const int scol = ((t & 7) * 8) ^ ((srow & 7) * 8);

    for (int pass = 0; pass < 2; pass++) {
        const int T = pass ? (15 - (int)blockIdx.x) : (int)blockIdx.x;
        const int q0w = T * 128 + wid * 32;
        const int nkb = 2 * T + 2;

        bf16x8 qf0[2], qf1[2];
        #pragma unroll
        for (int f = 0; f < 2; f++) {
            const uint16_t* Qp = Q + ((size_t)(b * Sn + q0w + f * 16 + l15)) * Dn + h * DHn + l4 * 8;
            qf0[f] = *(const bf16x8*)Qp;
            qf1[f] = *(const bf16x8*)(Qp + 32);
        }

        f32x4 acc[2][4];
        #pragma unroll
        for (int f = 0; f < 2; f++)
            #pragma unroll
            for (int db = 0; db < 4; db++) acc[f][db] = f32x4{0.f, 0.f, 0.f, 0.f};
        float m_[2] = {-INFINITY, -INFINITY};
        float lp[2] = {0.f, 0.f};

        #pragma unroll
        for (int it = 0; it < 2; it++) {
            const int row = srow + it * 32;
            load16_to_lds(Kbase + (size_t)row * Dn + scol, &lK[0][(size_t)(t + it * 256) * 8]);
            load16_to_lds(Vbase + (size_t)row * Sn + scol, &lV[0][(size_t)(t + it * 256) * 8]);
        }
        __syncthreads();

        int cur = 0;
        for (int kb = 0; kb < nkb; kb++) {
            if (kb + 1 < nkb) {
                const int kv1 = (kb + 1) * 64;
                #pragma unroll
                for (int it = 0; it < 2; it++) {
                    const int row = srow + it * 32;
                    load16_to_lds(Kbase + (size_t)(kv1 + row) * Dn + scol,
                                  &lK[cur ^ 1][(size_t)(t + it * 256) * 8]);
                    load16_to_lds(Vbase + (size_t)row * Sn + kv1 + scol,
                                  &lV[cur ^ 1][(size_t)(t + it * 256) * 8]);
                }
            }

            bf16x8 kf[4][2];
            #pragma unroll
            for (int c = 0; c < 4; c++) {
                const int row = c * 16 + l15;
                const int base = row * 64;
                const int off0 = (l4 * 8) ^ ((l15 & 7) * 8);
                const int off1 = (l4 * 8 + 32) ^ ((l15 & 7) * 8);
                kf[c][0] = *(const bf16x8*)&lK[cur][base + off0];
                kf[c][1] = *(const bf16x8*)&lK[cur][base + off1];
            }
            u16x4 vt4[4][4];
            #pragma unroll
            for (int db = 0; db < 4; db++) {
                const int base = (db * 16 + l15) * 64;
                const int sw = (l15 & 7) * 8;
                #pragma unroll
                for (int cc = 0; cc < 4; cc++)
                    vt4[cc][db] = *(const u16x4*)&lV[cur][base + ((cc * 16 + l4 * 4) ^ sw)];
            }

            f32x4 st[2][4];
            #pragma unroll
            for (int f = 0; f < 2; f++)
                #pragma unroll
                for (int c = 0; c < 4; c++) {
                    f32x4 z = mfma16(kf[c][0], qf0[f], f32x4{0.f, 0.f, 0.f, 0.f});
                    st[f][c] = mfma16(kf[c][1], qf1[f], z);
                }

            if (kb * 64 + 63 > q0w) {
                #pragma unroll
                for (int f = 0; f < 2; f++) {
                    const int qrow = q0w + f * 16 + l15;
                    #pragma unroll
                    for (int c = 0; c < 4; c++) {
                        const int kvb = kb * 64 + c * 16 + l4 * 4;
                        #pragma unroll
                        for (int r = 0; r < 4; r++)
                            if (kvb + r > qrow) st[f][c][r] = -INFINITY;
                    }
                }
            }

            #pragma unroll
            for (int f = 0; f < 2; f++) {
                float mxl = -INFINITY;
                #pragma unroll
                for (int c = 0; c < 4; c++)
                    mxl = fmaxf(mxl, fmaxf(fmaxf(st[f][c][0], st[f][c][1]),
                                           fmaxf(st[f][c][2], st[f][c][3])));
                if (!__all(mxl <= m_[f] + 8.0f)) {
                    float mx = mxl;
                    mx = fmaxf(mx, __shfl_xor(mx, 16));
                    mx = fmaxf(mx, __shfl_xor(mx, 32));
                    float mnew = fmaxf(m_[f], mx);
                    float sf = __expf(m_[f] - mnew);
                    m_[f] = mnew;
                    lp[f] *= sf;
                    #pragma unroll
                    for (int db = 0; db < 4; db++) {
                        acc[f][db][0] *= sf; acc[f][db][1] *= sf;
                        acc[f][db][2] *= sf; acc[f][db][3] *= sf;
                    }
                }
                #pragma unroll
                for (int c = 0; c < 4; c++) {
                    float p0 = __expf(st[f][c][0] - m_[f]);
                    float p1 = __expf(st[f][c][1] - m_[f]);
                    float p2 = __expf(st[f][c][2] - m_[f]);
                    float p3 = __expf(st[f][c][3] - m_[f]);
                    lp[f] += (p0 + p1) + (p2 + p3);
                    union { u16x4 v; uint32_t w[2]; } pf;
                    pf.w[0] = cvt2bf(p0, p1);
                    pf.w[1] = cvt2bf(p2, p3);
                    #pragma unroll
                    for (int db = 0; db < 4; db++)
                        acc[f][db] = mfma16k16(vt4[c][db], pf.v, acc[f][db]);
                }
            }

            __syncthreads();
            cur ^= 1;
        }

        #pragma unroll
        for (int f = 0; f < 2; f++) {
            float lt = lp[f];
            lt += __shfl_xor(lt, 16);
            lt += __shfl_xor(lt, 32);
            float inv = 1.0f / lt;
            const int qrow = q0w + f * 16 + l15;
            uint16_t* Op = O + ((size_t)(b * Sn + qrow)) * Dn + h * DHn;
            #pragma unroll
            for (int db = 0; db < 4; db++) {
                u16x4 o4;
                #pragma unroll
                for (int r = 0; r < 4; r++) o4[r] = f2bf_bits(acc[f][db][r] * inv);
                *(u16x4*)&Op[db * 16 + l4 * 4] = o4;
            }
        }
    }
}

// ---------------- launcher ----------------
extern "C" void kernel_launch(void* const* d_in, const int* in_sizes, int n_in,
                              void* d_out, int out_size, void* d_ws, size_t ws_size,
                              hipStream_t stream) {
    const float* x  = (const float*)d_in[0];
    const float* Wq = (const float*)d_in[1];
    const float* Wk = (const float*)d_in[2];
    const float* Wv = (const float*)d_in[3];
    const float* Wo = (const float*)d_in[4];

    char* ws = (char*)d_ws;
    uint16_t* xb   = (uint16_t*)(ws);                       // 16 MB
    uint16_t* wt   = (uint16_t*)(ws + 16777216);            // 8 MB  (4 x 1M elems: Wq,Wk,Wv,Wo)
    uint16_t* q    = (uint16_t*)(ws + 25165824);            // 16 MB
    uint16_t* k    = (uint16_t*)(ws + 41943040);            // 16 MB
    uint16_t* vt   = (uint16_t*)(ws + 58720256);            // 16 MB
    uint16_t* attn = (uint16_t*)(ws + 75497472);            // 16 MB
    float*    ct   = (float*)(ws + 92274688);               // 256 KB
    float*    st   = (float*)(ws + 92536832);               // 256 KB

    cast_x_k<<<8192, 256, 0, stream>>>(x, xb);
    transpose_cast_w<<<dim3(32, 32, 4), dim3(32, 32), 0, stream>>>(Wq, Wk, Wv, Wo, wt);
    rope_table_k<<<256, 256, 0, stream>>>(ct, st);

    // fused QKV GEMM over stacked [Wq^T;Wk^T;Wv^T] (first 3 MB of wt)
    gemm_qkv_k<<<dim3(64, 24), 256, 0, stream>>>(xb, wt, q, k, vt);

    rope_apply_k<<<dim3(4096, 2), 256, 0, stream>>>(q, k, ct, st);

    attn_k<<<dim3(8, Bn * Hn), 256, 0, stream>>>(q, k, vt, attn);

    gemm_out_k<<<dim3(64, 8), 256, 0, stream>>>(attn, wt + 3 * (size_t)Dn * Dn, (float*)d_out);
}